// Round 14
// baseline (426.856 us; speedup 1.0000x reference)
//
#include <hip/hip_runtime.h>
#include <hip/hip_bf16.h>
#include <stdint.h>

#define DDIM 512
#define NHEAD 8
#define BATCH 4
#define LTOK 24576
#define MROWS 98304          // BATCH * LTOK
#define MPNL 384             // M-panels of 256 rows
#define KVCH 96              // 256-token chunks per batch
#define PTILE 4160           // 64*64 kv + 64 ksum

typedef __attribute__((ext_vector_type(8))) short short8;
typedef __attribute__((ext_vector_type(4))) float f32x4;

__device__ __forceinline__ float bf2f(unsigned short u) {
  union { unsigned int i; float f; } c; c.i = ((unsigned int)u) << 16; return c.f;
}
__device__ __forceinline__ unsigned short f2bf(float f) {
  __hip_bfloat16 h = __float2bfloat16(f);
  return __builtin_bit_cast(unsigned short, h);
}
__device__ __forceinline__ void gload16(const void* g, void* l) {
  __builtin_amdgcn_global_load_lds((const __attribute__((address_space(1))) void*)g,
                                   (__attribute__((address_space(3))) void*)l, 16, 0, 0);
}
__device__ __forceinline__ float elu1(float v) { return (v > 0.f) ? (v + 1.f) : __expf(v); }

// ---------------- weight prep ----------------
__global__ __launch_bounds__(256) void wprep(const float* __restrict__ Wq, const float* __restrict__ bq,
                                             const float* __restrict__ Wk, const float* __restrict__ bk,
                                             const float* __restrict__ Wv, const float* __restrict__ bv,
                                             const float* __restrict__ Wo,
                                             unsigned short* __restrict__ wf,
                                             unsigned short* __restrict__ wob,
                                             float* __restrict__ biasf) {
  long t = (long)blockIdx.x * 256 + threadIdx.x;
  if (t < 786432) {
    int f = (int)(t >> 9), c = (int)(t & 511);
    const float* src;
    if (f < 1024) { int hh = f >> 7, kv = (f >> 6) & 1, d = f & 63;
                    src = (kv ? Wv : Wk) + (long)(hh * 64 + d) * 512; }
    else          src = Wq + (long)(f - 1024) * 512;
    wf[t] = f2bf(src[c]);
  } else if (t < 786432 + 262144) {
    long i = t - 786432; wob[i] = f2bf(Wo[i]);
  } else if (t < 786432 + 262144 + 1536) {
    int f = (int)(t - (786432 + 262144));
    float v;
    if (f < 1024) { int hh = f >> 7, kv = (f >> 6) & 1, d = f & 63; v = (kv ? bv : bk)[hh * 64 + d]; }
    else v = bq[f - 1024];
    biasf[f] = v;
  }
}

// ---------------- LayerNorm ----------------
__global__ __launch_bounds__(256) void ln_kernel(const float* __restrict__ x,
                                                 const float* __restrict__ g,
                                                 const float* __restrict__ b,
                                                 unsigned short* __restrict__ h) {
  int wv = threadIdx.x >> 6, lane = threadIdx.x & 63;
  long row = (long)blockIdx.x * 4 + wv;
  const float* xr = x + row * DDIM + lane * 8;
  float4 v0 = *(const float4*)xr;
  float4 v1 = *(const float4*)(xr + 4);
  float s  = v0.x + v0.y + v0.z + v0.w + v1.x + v1.y + v1.z + v1.w;
  float s2 = v0.x*v0.x + v0.y*v0.y + v0.z*v0.z + v0.w*v0.w
           + v1.x*v1.x + v1.y*v1.y + v1.z*v1.z + v1.w*v1.w;
  #pragma unroll
  for (int o = 32; o; o >>= 1) { s += __shfl_xor(s, o); s2 += __shfl_xor(s2, o); }
  float mu = s * (1.0f / DDIM);
  float var = s2 * (1.0f / DDIM) - mu * mu;
  float rs = rsqrtf(var + 1e-5f);
  float4 g0 = *(const float4*)(g + lane * 8);
  float4 g1 = *(const float4*)(g + lane * 8 + 4);
  float4 b0 = *(const float4*)(b + lane * 8);
  float4 b1 = *(const float4*)(b + lane * 8 + 4);
  short8 o;
  o[0] = (short)f2bf((v0.x - mu) * rs * g0.x + b0.x);
  o[1] = (short)f2bf((v0.y - mu) * rs * g0.y + b0.y);
  o[2] = (short)f2bf((v0.z - mu) * rs * g0.z + b0.z);
  o[3] = (short)f2bf((v0.w - mu) * rs * g0.w + b0.w);
  o[4] = (short)f2bf((v1.x - mu) * rs * g1.x + b1.x);
  o[5] = (short)f2bf((v1.y - mu) * rs * g1.y + b1.y);
  o[6] = (short)f2bf((v1.z - mu) * rs * g1.z + b1.z);
  o[7] = (short)f2bf((v1.w - mu) * rs * g1.w + b1.w);
  *(short8*)(h + row * DDIM + lane * 8) = o;
}

// ---------------- 256x128 / BK=32 / triple-buffered / 4-wave (128x64 per wave) K-loop ----------------
// LDS (shorts): A slots s=0..2 at s*8192 (256x32); B slots at 24576 + s*4096 (128x32).
// 72 KB -> 2 blocks/CU. 4 waves, per-wave 128x64: 32 MFMA per 12 ds_read_b128 (reuse 2.67).
// Swizzle: chunk ^= (row>>1)&3 on both pre-swizzled global source and ds_read.

__device__ __forceinline__ short8 ldsfrag(const unsigned short* h, int row, int kg) {
  return *(const short8*)&h[row * 32 + ((kg ^ ((row >> 1) & 3)) << 3)];
}

__device__ __forceinline__ void stageA(const unsigned short* g, unsigned short* l, int tid) {
  #pragma unroll
  for (int i = 0; i < 4; i++) {
    int c = i * 256 + tid;                // 1024 chunks (256 rows x 4)
    int rr = c >> 2, cc = c & 3;
    int sc = ((cc ^ ((rr >> 1) & 3)) << 3);
    gload16(g + (long)rr * DDIM + sc, l + c * 8);
  }
}
__device__ __forceinline__ void stageB(const unsigned short* g, unsigned short* l, int tid) {
  #pragma unroll
  for (int i = 0; i < 2; i++) {
    int c = i * 256 + tid;                // 512 chunks (128 rows x 4)
    int rr = c >> 2, cc = c & 3;
    int sc = ((cc ^ ((rr >> 1) & 3)) << 3);
    gload16(g + (long)rr * DDIM + sc, l + c * 8);
  }
}

// tile T reads slot T%3; stages T+2 into slot (T+2)%3. 6 loads/thread/stage ->
// counted vmcnt(6): T+1's loads landed, T+2's 6 outstanding. ONE barrier per tile.
template <int T>
__device__ __forceinline__ void ktileU(unsigned short* lds,
                                       const unsigned short* Ab, const unsigned short* Wb,
                                       f32x4 (&acc)[8][4],
                                       int wm, int wn, int lr, int kg, int tid) {
  constexpr int RS = T % 3;
  const unsigned short* As = lds + RS * 8192;
  const unsigned short* Bs = lds + 24576 + RS * 4096;
  short8 a[8], b[4];
  #pragma unroll
  for (int m = 0; m < 8; m++) a[m] = ldsfrag(As, wm * 128 + m * 16 + lr, kg);
  #pragma unroll
  for (int n = 0; n < 4; n++) b[n] = ldsfrag(Bs, wn * 64 + n * 16 + lr, kg);
  if constexpr (T < 14) {
    constexpr int S = (T + 2) % 3;
    stageA(Ab + (long)(T + 2) * 32, lds + S * 8192, tid);
    stageB(Wb + (long)(T + 2) * 32, lds + 24576 + S * 4096, tid);
  }
  __builtin_amdgcn_s_setprio(1);
  #pragma unroll
  for (int m = 0; m < 8; m++)
    #pragma unroll
    for (int n = 0; n < 4; n++)
      acc[m][n] = __builtin_amdgcn_mfma_f32_16x16x32_bf16(a[m], b[n], acc[m][n], 0, 0, 0);
  __builtin_amdgcn_s_setprio(0);
  if constexpr (T < 14)       { asm volatile("s_waitcnt vmcnt(6)" ::: "memory"); }
  else if constexpr (T == 14) { asm volatile("s_waitcnt vmcnt(0)" ::: "memory"); }
  if constexpr (T < 15) {
    __builtin_amdgcn_s_barrier();
    __builtin_amdgcn_sched_barrier(0);
  }
}

__device__ __forceinline__ void kloopU(unsigned short* lds,
                                       const unsigned short* Ab, const unsigned short* Wb,
                                       f32x4 (&acc)[8][4],
                                       int wm, int wn, int lr, int kg, int tid) {
  stageA(Ab,      lds + 0 * 8192, tid);  stageB(Wb,      lds + 24576 + 0 * 4096, tid);
  stageA(Ab + 32, lds + 1 * 8192, tid);  stageB(Wb + 32, lds + 24576 + 1 * 4096, tid);
  asm volatile("s_waitcnt vmcnt(6)" ::: "memory");   // tile0 landed (tile1's 6 in flight)
  __builtin_amdgcn_s_barrier();
  __builtin_amdgcn_sched_barrier(0);

  ktileU<0 >(lds, Ab, Wb, acc, wm, wn, lr, kg, tid);
  ktileU<1 >(lds, Ab, Wb, acc, wm, wn, lr, kg, tid);
  ktileU<2 >(lds, Ab, Wb, acc, wm, wn, lr, kg, tid);
  ktileU<3 >(lds, Ab, Wb, acc, wm, wn, lr, kg, tid);
  ktileU<4 >(lds, Ab, Wb, acc, wm, wn, lr, kg, tid);
  ktileU<5 >(lds, Ab, Wb, acc, wm, wn, lr, kg, tid);
  ktileU<6 >(lds, Ab, Wb, acc, wm, wn, lr, kg, tid);
  ktileU<7 >(lds, Ab, Wb, acc, wm, wn, lr, kg, tid);
  ktileU<8 >(lds, Ab, Wb, acc, wm, wn, lr, kg, tid);
  ktileU<9 >(lds, Ab, Wb, acc, wm, wn, lr, kg, tid);
  ktileU<10>(lds, Ab, Wb, acc, wm, wn, lr, kg, tid);
  ktileU<11>(lds, Ab, Wb, acc, wm, wn, lr, kg, tid);
  ktileU<12>(lds, Ab, Wb, acc, wm, wn, lr, kg, tid);
  ktileU<13>(lds, Ab, Wb, acc, wm, wn, lr, kg, tid);
  ktileU<14>(lds, Ab, Wb, acc, wm, wn, lr, kg, tid);
  ktileU<15>(lds, Ab, Wb, acc, wm, wn, lr, kg, tid);
}

// ---------------- fused QKV GEMM (256x128 blocks, 4 waves; y<8: kv head; y>=8: q quarter) ----------------
__global__ __launch_bounds__(256, 2) void qkv_gemm(const unsigned short* __restrict__ A,
                                                   const unsigned short* __restrict__ wf,
                                                   const float* __restrict__ biasf,
                                                   unsigned short* __restrict__ qbuf,
                                                   unsigned short* __restrict__ part) {
  __shared__ unsigned short lds[38016];   // 76 KB

  int tid = threadIdx.x;
  int wv = tid >> 6, lane = tid & 63;
  int wm = wv >> 1, wn = wv & 1;          // 2M x 2N wave grid, 128x64 per wave
  int kg = lane >> 4, lr = lane & 15;

  // XCD swizzle: groups of 96 = 8 xcd-slots x 12 y-siblings
  int lin = blockIdx.x;
  int g = lin / 96, r = lin % 96;
  int xb = g * 8 + (r & 7);               // 0..383
  int y  = r >> 3;                        // 0..11 (0-7 kv heads, 8-11 q quarters)
  long mBase = (long)xb * 256;
  int nBase = y * 128;

  const unsigned short* Ab = A + mBase * DDIM;
  const unsigned short* Wb = wf + (long)nBase * DDIM;

  f32x4 acc[8][4];
  #pragma unroll
  for (int m = 0; m < 8; m++)
    #pragma unroll
    for (int n = 0; n < 4; n++) acc[m][n] = (f32x4){0.f, 0.f, 0.f, 0.f};

  kloopU(lds, Ab, Wb, acc, wm, wn, lr, kg, tid);
  __syncthreads();

  if (y < 8) {
    // ---- one kv head: transpose, then P-MFMA over 256 tokens ----
    unsigned short* kT = lds;             // [64][264]
    unsigned short* vT = lds + 16896;     // [80][264] (rows 64..79: ones trick for ksum)
    int batch = xb / KVCH;
    int cIdx  = xb % KVCH;

    #pragma unroll
    for (int i = 0; i < 2; i++) {
      int idx = i * 256 + tid;
      int rr = 64 + (idx >> 5), cc = idx & 31;
      short8 z;
      #pragma unroll
      for (int j = 0; j < 8; j++) z[j] = (rr == 64) ? (short)0x3F80 : (short)0;
      *(short8*)&vT[rr * 264 + cc * 8] = z;
    }

    // transpose-write: wn=0 waves -> k (elu+1), wn=1 -> v; wm covers 128-token halves
    #pragma unroll
    for (int n = 0; n < 4; n++) {
      int feat = n * 16 + lr;             // 0..63
      float bv = biasf[nBase + wn * 64 + feat];
      #pragma unroll
      for (int m = 0; m < 8; m++)
        #pragma unroll
        for (int j = 0; j < 4; j++) {
          int tok = wm * 128 + m * 16 + kg * 4 + j;   // 0..255
          float v = acc[m][n][j] + bv;
          if (wn == 0) kT[feat * 264 + tok] = f2bf(elu1(v));
          else         vT[feat * 264 + tok] = f2bf(v);
        }
    }
    __syncthreads();

    // P = kT @ vT^T over 256 tokens; wave wv owns d-tile wv, loops 5 e-tiles (4 + ksum)
    int mt = wv;
    long pbase = ((long)(batch * 8 + y) * KVCH + cIdx) * PTILE;
    f32x4 pa[5];
    #pragma unroll
    for (int et = 0; et < 5; et++) pa[et] = (f32x4){0.f, 0.f, 0.f, 0.f};
    #pragma unroll
    for (int kk = 0; kk < 8; kk++) {
      short8 af = *(const short8*)&kT[(mt * 16 + lr) * 264 + kk * 32 + kg * 8];
      #pragma unroll
      for (int et = 0; et < 5; et++) {
        short8 bt = *(const short8*)&vT[(et * 16 + lr) * 264 + kk * 32 + kg * 8];
        pa[et] = __builtin_amdgcn_mfma_f32_16x16x32_bf16(af, bt, pa[et], 0, 0, 0);
      }
    }
    #pragma unroll
    for (int j = 0; j < 4; j++) {
      int d = mt * 16 + kg * 4 + j;
      #pragma unroll
      for (int et = 0; et < 4; et++)
        part[pbase + d * 64 + et * 16 + lr] = f2bf(pa[et][j]);
      if (lr == 0) part[pbase + 4096 + d] = f2bf(pa[4][j]);    // ksum column (e==64)
    }
  } else {
    // ---- q quarter: elu+1, single-pass LDS stage, coalesced write ----
    unsigned short* Cs = lds;             // [256][136]
    int qc0 = (y - 8) * 128;
    #pragma unroll
    for (int n = 0; n < 4; n++) {
      int col = wn * 64 + n * 16 + lr;    // 0..127
      float bv = biasf[nBase + col];
      #pragma unroll
      for (int m = 0; m < 8; m++)
        #pragma unroll
        for (int j = 0; j < 4; j++) {
          int row = wm * 128 + m * 16 + kg * 4 + j;   // 0..255
          Cs[row * 136 + col] = f2bf(elu1(acc[m][n][j] + bv));
        }
    }
    __syncthreads();
    #pragma unroll
    for (int i = 0; i < 16; i++) {
      int idx = i * 256 + tid;
      int row = idx >> 4, ch = idx & 15;
      *(short8*)&qbuf[(mBase + row) * DDIM + qc0 + ch * 8] =
          *(const short8*)&Cs[row * 136 + ch * 8];
    }
  }
}

// ---------------- reduce partials (coalesced short8): kvD bf16, ksum fp32 ----------------
__global__ __launch_bounds__(256) void kv_final(const unsigned short* __restrict__ part,
                                                unsigned short* __restrict__ kvD,
                                                float* __restrict__ ksum) {
  int bh = blockIdx.x;
  int gidx = blockIdx.y * 256 + threadIdx.x;
  if (gidx >= 520) return;                 // 520*8 = 4160 = PTILE
  long idx0 = (long)gidx * 8;
  const unsigned short* base = part + (long)bh * KVCH * PTILE + idx0;
  float s[8];
  #pragma unroll
  for (int j = 0; j < 8; j++) s[j] = 0.f;
  #pragma unroll 4
  for (int c = 0; c < KVCH; c++) {
    short8 v = *(const short8*)(base + (long)c * PTILE);
    #pragma unroll
    for (int j = 0; j < 8; j++) s[j] += bf2f((unsigned short)v[j]);
  }
  if (idx0 < 4096) {
    short8 o;
    #pragma unroll
    for (int j = 0; j < 8; j++) o[j] = (short)f2bf(s[j]);
    *(short8*)&kvD[bh * 4096 + idx0] = o;
  } else {
    int d0 = (int)(idx0 - 4096);
    #pragma unroll
    for (int j = 0; j < 8; j++) ksum[bh * 64 + d0 + j] = s[j];
  }
}

// ---------------- W2[b,h] = kv_h @ Wo_h^T -> Bmat[b][c][h*64+d] ----------------
__global__ __launch_bounds__(512) void w2_gemm(const unsigned short* __restrict__ kvD,
                                               const unsigned short* __restrict__ wob,
                                               unsigned short* __restrict__ Bmat) {
  __shared__ unsigned short W2s[512 * 72];
  int t = threadIdx.x, wv = t >> 6, lane = t & 63;
  int kg = lane >> 4, lr = lane & 15;
  int bh = blockIdx.x, b = bh >> 3, h = bh & 7;
  const unsigned short* kva = kvD + bh * 4096;

  short8 a[4][2];
  #pragma unroll
  for (int m = 0; m < 4; m++)
    #pragma unroll
    for (int kk = 0; kk < 2; kk++)
      a[m][kk] = *(const short8*)&kva[(m * 16 + lr) * 64 + kk * 32 + kg * 8];

  f32x4 acc[4][4];
  #pragma unroll
  for (int m = 0; m < 4; m++)
    #pragma unroll
    for (int n = 0; n < 4; n++) acc[m][n] = (f32x4){0.f, 0.f, 0.f, 0.f};

  #pragma unroll
  for (int n = 0; n < 4; n++) {
    int c = wv * 64 + n * 16 + lr;
    #pragma unroll
    for (int kk = 0; kk < 2; kk++) {
      short8 bfr = *(const short8*)&wob[(long)c * 512 + h * 64 + kk * 32 + kg * 8];
      #pragma unroll
      for (int m = 0; m < 4; m++)
        acc[m][n] = __builtin_amdgcn_mfma_f32_16x16x32_bf16(a[m][kk], bfr, acc[m][n], 0, 0, 0);
    }
  }
  #pragma unroll
  for (int m = 0; m < 4; m++)
    #pragma unroll
    for (int n = 0; n < 4; n++)
      #pragma unroll
      for (int j = 0; j < 4; j++)
        W2s[(wv * 64 + n * 16 + lr) * 72 + m * 16 + kg * 4 + j] = f2bf(acc[m][n][j]);
  __syncthreads();
  #pragma unroll
  for (int pp = 0; pp < 8; pp++) {
    int idx = pp * 512 + t;
    int c = idx >> 3, ch = (idx & 7) * 8;
    *(short8*)&Bmat[(long)b * 262144 + (long)c * 512 + h * 64 + ch] =
        *(const short8*)&W2s[c * 72 + ch];
  }
}

// ---------------- qs = q / (q . ksum_h + eps) ----------------
__global__ __launch_bounds__(256) void qscale(unsigned short* __restrict__ q,
                                              const float* __restrict__ ksum) {
  int wv = threadIdx.x >> 6, lane = threadIdx.x & 63;
  long row = (long)blockIdx.x * 4 + wv;
  int batch = (int)(row / LTOK);
  int bh = batch * 8 + (lane >> 3);
  unsigned short* qr = q + row * DDIM + lane * 8;
  short8 qv = *(const short8*)qr;
  const float* ks = ksum + bh * 64 + (lane & 7) * 8;
  float4 k0 = *(const float4*)ks;
  float4 k1 = *(const float4*)(ks + 4);
  float qf[8];
  #pragma unroll
  for (int j = 0; j < 8; j++) qf[j] = bf2f((unsigned short)qv[j]);
  float n = qf[0]*k0.x + qf[1]*k0.y + qf[2]*k0.z + qf[3]*k0.w
          + qf[4]*k1.x + qf[5]*k1.y + qf[6]*k1.z + qf[7]*k1.w;
  n += __shfl_xor(n, 1);
  n += __shfl_xor(n, 2);
  n += __shfl_xor(n, 4);
  float s = 1.0f / (n + 1e-6f);
  short8 o;
  #pragma unroll
  for (int j = 0; j < 8; j++) o[j] = (short)f2bf(qf[j] * s);
  *(short8*)qr = o;
}

// ---------------- final GEMM (256x128, 4-wave kloop): out = qs @ Bmat[b]^T + bo + x ----------------
__global__ __launch_bounds__(256, 2) void ogemm(const unsigned short* __restrict__ A,
                                                const unsigned short* __restrict__ Bm,
                                                const float* __restrict__ bo,
                                                const float* __restrict__ xres,
                                                float* __restrict__ out) {
  __shared__ unsigned short lds[38016];   // K-loop 72 KB; epilogue fp32 [128][132] = 66 KB

  int tid = threadIdx.x;
  int wv = tid >> 6, lane = tid & 63;
  int wm = wv >> 1, wn = wv & 1;          // 2M x 2N, 128x64 per wave
  int kg = lane >> 4, lr = lane & 15;

  // XCD swizzle: groups of 32 = 8 xcd-slots x 4 y-siblings
  int lin = blockIdx.x;
  int g = lin >> 5, r = lin & 31;
  int xb = g * 8 + (r & 7);               // 0..383
  int y  = r >> 3;                        // 0..3
  long mBase = (long)xb * 256;
  int nBase = y * 128;
  int batch = xb / KVCH;

  const unsigned short* Ab = A + mBase * DDIM;
  const unsigned short* Wb = Bm + (long)batch * 262144 + (long)nBase * DDIM;

  f32x4 acc[8][4];
  #pragma unroll
  for (int m = 0; m < 8; m++)
    #pragma unroll
    for (int n = 0; n < 4; n++) acc[m][n] = (f32x4){0.f, 0.f, 0.f, 0.f};

  kloopU(lds, Ab, Wb, acc, wm, wn, lr, kg, tid);
  __syncthreads();

  // epilogue: +bo, +residual; two 128-row rounds (wave wm==rr writes its rows)
  float* Cs = (float*)lds;                // [128][132]
  #pragma unroll 1
  for (int rr = 0; rr < 2; rr++) {
    if (wm == rr) {
      #pragma unroll
      for (int n = 0; n < 4; n++) {
        int col = wn * 64 + n * 16 + lr;
        float bv = bo[nBase + col];
        #pragma unroll
        for (int m = 0; m < 8; m++)
          #pragma unroll
          for (int j = 0; j < 4; j++) {
            int lrow = m * 16 + kg * 4 + j;
            Cs[lrow * 132 + col] = acc[m][n][j] + bv;
          }
      }
    }
    __syncthreads();
    #pragma unroll
    for (int it = 0; it < 16; it++) {
      int idx = it * 256 + tid;
      int row = idx >> 5, c4 = idx & 31;
      long goff = (mBase + rr * 128 + row) * DDIM + nBase + c4 * 4;
      float4 rv = *(const float4*)&xres[goff];
      float4 cv = *(const float4*)&Cs[row * 132 + c4 * 4];
      float4 ov; ov.x = cv.x + rv.x; ov.y = cv.y + rv.y; ov.z = cv.z + rv.z; ov.w = cv.w + rv.w;
      *(float4*)&out[goff] = ov;
    }
    __syncthreads();
  }
}

// ---------------- launcher ----------------
extern "C" void kernel_launch(void* const* d_in, const int* in_sizes, int n_in,
                              void* d_out, int out_size, void* d_ws, size_t ws_size,
                              hipStream_t stream) {
  const float* x    = (const float*)d_in[0];
  const float* Wq   = (const float*)d_in[1];
  const float* bq   = (const float*)d_in[2];
  const float* Wk   = (const float*)d_in[3];
  const float* bk   = (const float*)d_in[4];
  const float* Wv   = (const float*)d_in[5];
  const float* bv   = (const float*)d_in[6];
  const float* Wo   = (const float*)d_in[7];
  const float* bo   = (const float*)d_in[8];
  const float* ln_g = (const float*)d_in[9];
  const float* ln_b = (const float*)d_in[10];

  char* ws = (char*)d_ws;
  size_t SZ = (size_t)MROWS * DDIM * 2;
  unsigned short* hbuf = (unsigned short*)ws;
  unsigned short* qbuf = (unsigned short*)(ws + SZ);
  char* p = ws + 2 * SZ;
  unsigned short* wf   = (unsigned short*)p;  p += (size_t)1536 * 512 * 2;
  unsigned short* wob  = (unsigned short*)p;  p += (size_t)512 * 512 * 2;
  float* biasf         = (float*)p;           p += 1536 * 4;
  p = (char*)(((uintptr_t)p + 255) & ~(uintptr_t)255);
  unsigned short* part = (unsigned short*)p;  p += (size_t)32 * KVCH * PTILE * 2;   // 25.5 MB
  unsigned short* kvD  = (unsigned short*)p;  p += (size_t)32 * 4096 * 2;
  float* ksum          = (float*)p;           p += 32 * 64 * 4;
  p = (char*)(((uintptr_t)p + 255) & ~(uintptr_t)255);
  unsigned short* Bmat = (unsigned short*)p;  p += (size_t)BATCH * 512 * 512 * 2;

  wprep<<<(786432 + 262144 + 1536 + 255) / 256, 256, 0, stream>>>(Wq, bq, Wk, bk, Wv, bv, Wo,
                                                                  wf, wob, biasf);
  ln_kernel<<<MROWS / 4, 256, 0, stream>>>(x, ln_g, ln_b, hbuf);
  qkv_gemm<<<MPNL * 12, 256, 0, stream>>>(hbuf, wf, biasf, qbuf, part);
  kv_final<<<dim3(32, 3), 256, 0, stream>>>(part, kvD, ksum);
  w2_gemm<<<32, 512, 0, stream>>>(kvD, wob, Bmat);
  qscale<<<MROWS / 4, 256, 0, stream>>>(qbuf, ksum);
  ogemm<<<MPNL * 4, 256, 0, stream>>>(qbuf, Bmat, bo, x, (float*)d_out);
}

// Round 15
// 411.018 us; speedup vs baseline: 1.0385x; 1.0385x over previous
//
#include <hip/hip_runtime.h>
#include <hip/hip_bf16.h>
#include <stdint.h>

#define DDIM 512
#define NHEAD 8
#define BATCH 4
#define LTOK 24576
#define MROWS 98304          // BATCH * LTOK
#define MPNL 384             // M-panels of 256 rows
#define KVCH 96              // 256-token chunks per batch
#define PTILE 4160           // 64*64 kv + 64 ksum

typedef __attribute__((ext_vector_type(8))) short short8;
typedef __attribute__((ext_vector_type(4))) float f32x4;

__device__ __forceinline__ float bf2f(unsigned short u) {
  union { unsigned int i; float f; } c; c.i = ((unsigned int)u) << 16; return c.f;
}
__device__ __forceinline__ unsigned short f2bf(float f) {
  __hip_bfloat16 h = __float2bfloat16(f);
  return __builtin_bit_cast(unsigned short, h);
}
__device__ __forceinline__ void gload16(const void* g, void* l) {
  __builtin_amdgcn_global_load_lds((const __attribute__((address_space(1))) void*)g,
                                   (__attribute__((address_space(3))) void*)l, 16, 0, 0);
}
__device__ __forceinline__ float elu1(float v) { return (v > 0.f) ? (v + 1.f) : __expf(v); }

// ---------------- weight prep ----------------
__global__ __launch_bounds__(256) void wprep(const float* __restrict__ Wq, const float* __restrict__ bq,
                                             const float* __restrict__ Wk, const float* __restrict__ bk,
                                             const float* __restrict__ Wv, const float* __restrict__ bv,
                                             const float* __restrict__ Wo,
                                             unsigned short* __restrict__ wf,
                                             unsigned short* __restrict__ wob,
                                             float* __restrict__ biasf) {
  long t = (long)blockIdx.x * 256 + threadIdx.x;
  if (t < 786432) {
    int f = (int)(t >> 9), c = (int)(t & 511);
    const float* src;
    if (f < 1024) { int hh = f >> 7, kv = (f >> 6) & 1, d = f & 63;
                    src = (kv ? Wv : Wk) + (long)(hh * 64 + d) * 512; }
    else          src = Wq + (long)(f - 1024) * 512;
    wf[t] = f2bf(src[c]);
  } else if (t < 786432 + 262144) {
    long i = t - 786432; wob[i] = f2bf(Wo[i]);
  } else if (t < 786432 + 262144 + 1536) {
    int f = (int)(t - (786432 + 262144));
    float v;
    if (f < 1024) { int hh = f >> 7, kv = (f >> 6) & 1, d = f & 63; v = (kv ? bv : bk)[hh * 64 + d]; }
    else v = bq[f - 1024];
    biasf[f] = v;
  }
}

// ---------------- LayerNorm ----------------
__global__ __launch_bounds__(256) void ln_kernel(const float* __restrict__ x,
                                                 const float* __restrict__ g,
                                                 const float* __restrict__ b,
                                                 unsigned short* __restrict__ h) {
  int wv = threadIdx.x >> 6, lane = threadIdx.x & 63;
  long row = (long)blockIdx.x * 4 + wv;
  const float* xr = x + row * DDIM + lane * 8;
  float4 v0 = *(const float4*)xr;
  float4 v1 = *(const float4*)(xr + 4);
  float s  = v0.x + v0.y + v0.z + v0.w + v1.x + v1.y + v1.z + v1.w;
  float s2 = v0.x*v0.x + v0.y*v0.y + v0.z*v0.z + v0.w*v0.w
           + v1.x*v1.x + v1.y*v1.y + v1.z*v1.z + v1.w*v1.w;
  #pragma unroll
  for (int o = 32; o; o >>= 1) { s += __shfl_xor(s, o); s2 += __shfl_xor(s2, o); }
  float mu = s * (1.0f / DDIM);
  float var = s2 * (1.0f / DDIM) - mu * mu;
  float rs = rsqrtf(var + 1e-5f);
  float4 g0 = *(const float4*)(g + lane * 8);
  float4 g1 = *(const float4*)(g + lane * 8 + 4);
  float4 b0 = *(const float4*)(b + lane * 8);
  float4 b1 = *(const float4*)(b + lane * 8 + 4);
  short8 o;
  o[0] = (short)f2bf((v0.x - mu) * rs * g0.x + b0.x);
  o[1] = (short)f2bf((v0.y - mu) * rs * g0.y + b0.y);
  o[2] = (short)f2bf((v0.z - mu) * rs * g0.z + b0.z);
  o[3] = (short)f2bf((v0.w - mu) * rs * g0.w + b0.w);
  o[4] = (short)f2bf((v1.x - mu) * rs * g1.x + b1.x);
  o[5] = (short)f2bf((v1.y - mu) * rs * g1.y + b1.y);
  o[6] = (short)f2bf((v1.z - mu) * rs * g1.z + b1.z);
  o[7] = (short)f2bf((v1.w - mu) * rs * g1.w + b1.w);
  *(short8*)(h + row * DDIM + lane * 8) = o;
}

// ---------------- 256x128 / BK=32 / triple-buffered / 8-wave (64x64 per wave) K-loop ----------------
// LDS (shorts): A slots s=0..2 at s*8192 (256x32); B slots at 24576 + s*4096 (128x32).
// 72 KB -> 2 blocks/CU (16 waves/CU). Fully unrolled (R13 proven, 178 us).

__device__ __forceinline__ short8 ldsfrag(const unsigned short* h, int row, int kg) {
  return *(const short8*)&h[row * 32 + ((kg ^ ((row >> 1) & 3)) << 3)];
}

__device__ __forceinline__ void stageA(const unsigned short* g, unsigned short* l, int tid) {
  #pragma unroll
  for (int i = 0; i < 2; i++) {
    int c = i * 512 + tid;                // 1024 chunks (256 rows x 4)
    int rr = c >> 2, cc = c & 3;
    int sc = ((cc ^ ((rr >> 1) & 3)) << 3);
    gload16(g + (long)rr * DDIM + sc, l + c * 8);
  }
}
__device__ __forceinline__ void stageB(const unsigned short* g, unsigned short* l, int tid) {
  int c = tid;                            // 512 chunks (128 rows x 4)
  int rr = c >> 2, cc = c & 3;
  int sc = ((cc ^ ((rr >> 1) & 3)) << 3);
  gload16(g + (long)rr * DDIM + sc, l + c * 8);
}

template <int T>
__device__ __forceinline__ void ktileU(unsigned short* lds,
                                       const unsigned short* Ab, const unsigned short* Wb,
                                       f32x4 (&acc)[4][4],
                                       int wm, int wn, int lr, int kg, int tid) {
  constexpr int RS = T % 3;
  const unsigned short* As = lds + RS * 8192;
  const unsigned short* Bs = lds + 24576 + RS * 4096;
  short8 a[4], b[4];
  #pragma unroll
  for (int m = 0; m < 4; m++) a[m] = ldsfrag(As, wm * 64 + m * 16 + lr, kg);
  #pragma unroll
  for (int n = 0; n < 4; n++) b[n] = ldsfrag(Bs, wn * 64 + n * 16 + lr, kg);
  if constexpr (T < 14) {
    constexpr int S = (T + 2) % 3;
    stageA(Ab + (long)(T + 2) * 32, lds + S * 8192, tid);
    stageB(Wb + (long)(T + 2) * 32, lds + 24576 + S * 4096, tid);
  }
  __builtin_amdgcn_s_setprio(1);
  #pragma unroll
  for (int m = 0; m < 4; m++)
    #pragma unroll
    for (int n = 0; n < 4; n++)
      acc[m][n] = __builtin_amdgcn_mfma_f32_16x16x32_bf16(a[m], b[n], acc[m][n], 0, 0, 0);
  __builtin_amdgcn_s_setprio(0);
  if constexpr (T < 14)       { asm volatile("s_waitcnt vmcnt(3)" ::: "memory"); }
  else if constexpr (T == 14) { asm volatile("s_waitcnt vmcnt(0)" ::: "memory"); }
  if constexpr (T < 15) {
    __builtin_amdgcn_s_barrier();
    __builtin_amdgcn_sched_barrier(0);
  }
}

__device__ __forceinline__ void kloopU(unsigned short* lds,
                                       const unsigned short* Ab, const unsigned short* Wb,
                                       f32x4 (&acc)[4][4],
                                       int wm, int wn, int lr, int kg, int tid) {
  stageA(Ab,      lds + 0 * 8192, tid);  stageB(Wb,      lds + 24576 + 0 * 4096, tid);
  stageA(Ab + 32, lds + 1 * 8192, tid);  stageB(Wb + 32, lds + 24576 + 1 * 4096, tid);
  asm volatile("s_waitcnt vmcnt(3)" ::: "memory");   // tile0 landed (tile1's 3 in flight)
  __builtin_amdgcn_s_barrier();
  __builtin_amdgcn_sched_barrier(0);

  ktileU<0 >(lds, Ab, Wb, acc, wm, wn, lr, kg, tid);
  ktileU<1 >(lds, Ab, Wb, acc, wm, wn, lr, kg, tid);
  ktileU<2 >(lds, Ab, Wb, acc, wm, wn, lr, kg, tid);
  ktileU<3 >(lds, Ab, Wb, acc, wm, wn, lr, kg, tid);
  ktileU<4 >(lds, Ab, Wb, acc, wm, wn, lr, kg, tid);
  ktileU<5 >(lds, Ab, Wb, acc, wm, wn, lr, kg, tid);
  ktileU<6 >(lds, Ab, Wb, acc, wm, wn, lr, kg, tid);
  ktileU<7 >(lds, Ab, Wb, acc, wm, wn, lr, kg, tid);
  ktileU<8 >(lds, Ab, Wb, acc, wm, wn, lr, kg, tid);
  ktileU<9 >(lds, Ab, Wb, acc, wm, wn, lr, kg, tid);
  ktileU<10>(lds, Ab, Wb, acc, wm, wn, lr, kg, tid);
  ktileU<11>(lds, Ab, Wb, acc, wm, wn, lr, kg, tid);
  ktileU<12>(lds, Ab, Wb, acc, wm, wn, lr, kg, tid);
  ktileU<13>(lds, Ab, Wb, acc, wm, wn, lr, kg, tid);
  ktileU<14>(lds, Ab, Wb, acc, wm, wn, lr, kg, tid);
  ktileU<15>(lds, Ab, Wb, acc, wm, wn, lr, kg, tid);
}

// ---------------- fused QKV GEMM (256x128 blocks, 8 waves; y<8: kv head; y>=8: q quarter) ----------------
__global__ __launch_bounds__(512, 4) void qkv_gemm(const unsigned short* __restrict__ A,
                                                   const unsigned short* __restrict__ wf,
                                                   const float* __restrict__ biasf,
                                                   unsigned short* __restrict__ qbuf,
                                                   unsigned short* __restrict__ part) {
  __shared__ unsigned short lds[38016];   // 76 KB

  int tid = threadIdx.x;
  int wv = tid >> 6, lane = tid & 63;
  int wm = wv >> 1, wn = wv & 1;          // 4M x 2N wave grid, 64x64 per wave
  int kg = lane >> 4, lr = lane & 15;

  // XCD swizzle: groups of 96 = 8 xcd-slots x 12 y-siblings
  int lin = blockIdx.x;
  int g = lin / 96, r = lin % 96;
  int xb = g * 8 + (r & 7);               // 0..383
  int y  = r >> 3;                        // 0..11 (0-7 kv heads, 8-11 q quarters)
  long mBase = (long)xb * 256;
  int nBase = y * 128;

  const unsigned short* Ab = A + mBase * DDIM;
  const unsigned short* Wb = wf + (long)nBase * DDIM;

  f32x4 acc[4][4];
  #pragma unroll
  for (int m = 0; m < 4; m++)
    #pragma unroll
    for (int n = 0; n < 4; n++) acc[m][n] = (f32x4){0.f, 0.f, 0.f, 0.f};

  kloopU(lds, Ab, Wb, acc, wm, wn, lr, kg, tid);
  __syncthreads();

  if (y < 8) {
    // ---- one kv head: transpose all waves at once, P-MFMA over 256 tokens ----
    unsigned short* kT = lds;             // [64][264]
    unsigned short* vT = lds + 16896;     // [80][264] (rows 64..79: ones trick for ksum)
    int batch = xb / KVCH;
    int cIdx  = xb % KVCH;

    {
      int rr = 64 + (tid >> 5), cc = tid & 31;
      short8 z;
      #pragma unroll
      for (int j = 0; j < 8; j++) z[j] = (rr == 64) ? (short)0x3F80 : (short)0;
      *(short8*)&vT[rr * 264 + cc * 8] = z;
    }

    #pragma unroll
    for (int n = 0; n < 4; n++) {
      int feat = n * 16 + lr;             // 0..63
      float bv = biasf[nBase + wn * 64 + feat];
      #pragma unroll
      for (int m = 0; m < 4; m++)
        #pragma unroll
        for (int j = 0; j < 4; j++) {
          int tok = wm * 64 + m * 16 + kg * 4 + j;   // 0..255
          float v = acc[m][n][j] + bv;
          if (wn == 0) kT[feat * 264 + tok] = f2bf(elu1(v));
          else         vT[feat * 264 + tok] = f2bf(v);
        }
    }
    __syncthreads();

    int mt = wv & 3, ngrp = wv >> 2;
    long pbase = ((long)(batch * 8 + y) * KVCH + cIdx) * PTILE;
    if (!ngrp) {
      f32x4 pa0 = {0,0,0,0}, pa1 = {0,0,0,0}, pa2 = {0,0,0,0};
      #pragma unroll
      for (int kk = 0; kk < 8; kk++) {
        short8 af = *(const short8*)&kT[(mt * 16 + lr) * 264 + kk * 32 + kg * 8];
        short8 b0 = *(const short8*)&vT[(0 * 16 + lr) * 264 + kk * 32 + kg * 8];
        short8 b1 = *(const short8*)&vT[(1 * 16 + lr) * 264 + kk * 32 + kg * 8];
        short8 b2 = *(const short8*)&vT[(2 * 16 + lr) * 264 + kk * 32 + kg * 8];
        pa0 = __builtin_amdgcn_mfma_f32_16x16x32_bf16(af, b0, pa0, 0, 0, 0);
        pa1 = __builtin_amdgcn_mfma_f32_16x16x32_bf16(af, b1, pa1, 0, 0, 0);
        pa2 = __builtin_amdgcn_mfma_f32_16x16x32_bf16(af, b2, pa2, 0, 0, 0);
      }
      #pragma unroll
      for (int j = 0; j < 4; j++) {
        int d = mt * 16 + kg * 4 + j;
        part[pbase + d * 64 + (0 * 16 + lr)] = f2bf(pa0[j]);
        part[pbase + d * 64 + (1 * 16 + lr)] = f2bf(pa1[j]);
        part[pbase + d * 64 + (2 * 16 + lr)] = f2bf(pa2[j]);
      }
    } else {
      f32x4 pa0 = {0,0,0,0}, pa1 = {0,0,0,0};
      #pragma unroll
      for (int kk = 0; kk < 8; kk++) {
        short8 af = *(const short8*)&kT[(mt * 16 + lr) * 264 + kk * 32 + kg * 8];
        short8 b0 = *(const short8*)&vT[(3 * 16 + lr) * 264 + kk * 32 + kg * 8];
        short8 b1 = *(const short8*)&vT[(4 * 16 + lr) * 264 + kk * 32 + kg * 8];
        pa0 = __builtin_amdgcn_mfma_f32_16x16x32_bf16(af, b0, pa0, 0, 0, 0);
        pa1 = __builtin_amdgcn_mfma_f32_16x16x32_bf16(af, b1, pa1, 0, 0, 0);
      }
      #pragma unroll
      for (int j = 0; j < 4; j++) {
        int d = mt * 16 + kg * 4 + j;
        part[pbase + d * 64 + (3 * 16 + lr)] = f2bf(pa0[j]);
        if (lr == 0) part[pbase + 4096 + d] = f2bf(pa1[j]);   // ksum column (e==64)
      }
    }
  } else {
    // ---- q quarter: elu+1, single-pass LDS stage, coalesced write ----
    unsigned short* Cs = lds;             // [256][136]
    int qc0 = (y - 8) * 128;
    #pragma unroll
    for (int n = 0; n < 4; n++) {
      int col = wn * 64 + n * 16 + lr;    // 0..127
      float bv = biasf[nBase + col];
      #pragma unroll
      for (int m = 0; m < 4; m++)
        #pragma unroll
        for (int j = 0; j < 4; j++) {
          int row = wm * 64 + m * 16 + kg * 4 + j;   // 0..255
          Cs[row * 136 + col] = f2bf(elu1(acc[m][n][j] + bv));
        }
    }
    __syncthreads();
    #pragma unroll
    for (int i = 0; i < 8; i++) {
      int idx = i * 512 + tid;
      int row = idx >> 4, ch = idx & 15;
      *(short8*)&qbuf[(mBase + row) * DDIM + qc0 + ch * 8] =
          *(const short8*)&Cs[row * 136 + ch * 8];
    }
  }
}

// ---------------- reduce partials (coalesced short8): kvD bf16, ksum fp32 ----------------
__global__ __launch_bounds__(256) void kv_final(const unsigned short* __restrict__ part,
                                                unsigned short* __restrict__ kvD,
                                                float* __restrict__ ksum) {
  int bh = blockIdx.x;
  int gidx = blockIdx.y * 256 + threadIdx.x;
  if (gidx >= 520) return;                 // 520*8 = 4160 = PTILE
  long idx0 = (long)gidx * 8;
  const unsigned short* base = part + (long)bh * KVCH * PTILE + idx0;
  float s[8];
  #pragma unroll
  for (int j = 0; j < 8; j++) s[j] = 0.f;
  #pragma unroll 4
  for (int c = 0; c < KVCH; c++) {
    short8 v = *(const short8*)(base + (long)c * PTILE);
    #pragma unroll
    for (int j = 0; j < 8; j++) s[j] += bf2f((unsigned short)v[j]);
  }
  if (idx0 < 4096) {
    short8 o;
    #pragma unroll
    for (int j = 0; j < 8; j++) o[j] = (short)f2bf(s[j]);
    *(short8*)&kvD[bh * 4096 + idx0] = o;
  } else {
    int d0 = (int)(idx0 - 4096);
    #pragma unroll
    for (int j = 0; j < 8; j++) ksum[bh * 64 + d0 + j] = s[j];
  }
}

// ---------------- W2[b,h] = kv_h @ Wo_h^T -> Bmat[b][c][h*64+d] ----------------
__global__ __launch_bounds__(512) void w2_gemm(const unsigned short* __restrict__ kvD,
                                               const unsigned short* __restrict__ wob,
                                               unsigned short* __restrict__ Bmat) {
  __shared__ unsigned short W2s[512 * 72];
  int t = threadIdx.x, wv = t >> 6, lane = t & 63;
  int kg = lane >> 4, lr = lane & 15;
  int bh = blockIdx.x, b = bh >> 3, h = bh & 7;
  const unsigned short* kva = kvD + bh * 4096;

  short8 a[4][2];
  #pragma unroll
  for (int m = 0; m < 4; m++)
    #pragma unroll
    for (int kk = 0; kk < 2; kk++)
      a[m][kk] = *(const short8*)&kva[(m * 16 + lr) * 64 + kk * 32 + kg * 8];

  f32x4 acc[4][4];
  #pragma unroll
  for (int m = 0; m < 4; m++)
    #pragma unroll
    for (int n = 0; n < 4; n++) acc[m][n] = (f32x4){0.f, 0.f, 0.f, 0.f};

  #pragma unroll
  for (int n = 0; n < 4; n++) {
    int c = wv * 64 + n * 16 + lr;
    #pragma unroll
    for (int kk = 0; kk < 2; kk++) {
      short8 bfr = *(const short8*)&wob[(long)c * 512 + h * 64 + kk * 32 + kg * 8];
      #pragma unroll
      for (int m = 0; m < 4; m++)
        acc[m][n] = __builtin_amdgcn_mfma_f32_16x16x32_bf16(a[m][kk], bfr, acc[m][n], 0, 0, 0);
    }
  }
  #pragma unroll
  for (int m = 0; m < 4; m++)
    #pragma unroll
    for (int n = 0; n < 4; n++)
      #pragma unroll
      for (int j = 0; j < 4; j++)
        W2s[(wv * 64 + n * 16 + lr) * 72 + m * 16 + kg * 4 + j] = f2bf(acc[m][n][j]);
  __syncthreads();
  #pragma unroll
  for (int pp = 0; pp < 8; pp++) {
    int idx = pp * 512 + t;
    int c = idx >> 3, ch = (idx & 7) * 8;
    *(short8*)&Bmat[(long)b * 262144 + (long)c * 512 + h * 64 + ch] =
        *(const short8*)&W2s[c * 72 + ch];
  }
}

// ---------------- qs = q / (q . ksum_h + eps) ----------------
__global__ __launch_bounds__(256) void qscale(unsigned short* __restrict__ q,
                                              const float* __restrict__ ksum) {
  int wv = threadIdx.x >> 6, lane = threadIdx.x & 63;
  long row = (long)blockIdx.x * 4 + wv;
  int batch = (int)(row / LTOK);
  int bh = batch * 8 + (lane >> 3);
  unsigned short* qr = q + row * DDIM + lane * 8;
  short8 qv = *(const short8*)qr;
  const float* ks = ksum + bh * 64 + (lane & 7) * 8;
  float4 k0 = *(const float4*)ks;
  float4 k1 = *(const float4*)(ks + 4);
  float qf[8];
  #pragma unroll
  for (int j = 0; j < 8; j++) qf[j] = bf2f((unsigned short)qv[j]);
  float n = qf[0]*k0.x + qf[1]*k0.y + qf[2]*k0.z + qf[3]*k0.w
          + qf[4]*k1.x + qf[5]*k1.y + qf[6]*k1.z + qf[7]*k1.w;
  n += __shfl_xor(n, 1);
  n += __shfl_xor(n, 2);
  n += __shfl_xor(n, 4);
  float s = 1.0f / (n + 1e-6f);
  short8 o;
  #pragma unroll
  for (int j = 0; j < 8; j++) o[j] = (short)f2bf(qf[j] * s);
  *(short8*)qr = o;
}

// ---------------- final GEMM (256x128, 8-wave kloop): out = qs @ Bmat[b]^T + bo + x ----------------
__global__ __launch_bounds__(512, 4) void ogemm(const unsigned short* __restrict__ A,
                                                const unsigned short* __restrict__ Bm,
                                                const float* __restrict__ bo,
                                                const float* __restrict__ xres,
                                                float* __restrict__ out) {
  __shared__ unsigned short lds[38016];   // K-loop 72 KB; epilogue fp32 [128][132] = 66 KB

  int tid = threadIdx.x;
  int wv = tid >> 6, lane = tid & 63;
  int wm = wv >> 1, wn = wv & 1;          // 4M x 2N
  int kg = lane >> 4, lr = lane & 15;

  // XCD swizzle: groups of 32 = 8 xcd-slots x 4 y-siblings
  int lin = blockIdx.x;
  int g = lin >> 5, r = lin & 31;
  int xb = g * 8 + (r & 7);               // 0..383
  int y  = r >> 3;                        // 0..3
  long mBase = (long)xb * 256;
  int nBase = y * 128;
  int batch = xb / KVCH;

  const unsigned short* Ab = A + mBase * DDIM;
  const unsigned short* Wb = Bm + (long)batch * 262144 + (long)nBase * DDIM;

  f32x4 acc[4][4];
  #pragma unroll
  for (int m = 0; m < 4; m++)
    #pragma unroll
    for (int n = 0; n < 4; n++) acc[m][n] = (f32x4){0.f, 0.f, 0.f, 0.f};

  kloopU(lds, Ab, Wb, acc, wm, wn, lr, kg, tid);
  __syncthreads();

  // epilogue: +bo, +residual; two 128-row rounds through fp32 LDS staging
  float* Cs = (float*)lds;                // [128][132]
  #pragma unroll 1
  for (int rr = 0; rr < 2; rr++) {
    if ((wm >> 1) == rr) {
      #pragma unroll
      for (int n = 0; n < 4; n++) {
        int col = wn * 64 + n * 16 + lr;
        float bv = bo[nBase + col];
        #pragma unroll
        for (int m = 0; m < 4; m++)
          #pragma unroll
          for (int j = 0; j < 4; j++) {
            int lrow = (wm & 1) * 64 + m * 16 + kg * 4 + j;
            Cs[lrow * 132 + col] = acc[m][n][j] + bv;
          }
      }
    }
    __syncthreads();
    #pragma unroll
    for (int it = 0; it < 8; it++) {
      int idx = it * 512 + tid;
      int row = idx >> 5, c4 = idx & 31;
      long goff = (mBase + rr * 128 + row) * DDIM + nBase + c4 * 4;
      float4 rv = *(const float4*)&xres[goff];
      float4 cv = *(const float4*)&Cs[row * 132 + c4 * 4];
      float4 ov; ov.x = cv.x + rv.x; ov.y = cv.y + rv.y; ov.z = cv.z + rv.z; ov.w = cv.w + rv.w;
      *(float4*)&out[goff] = ov;
    }
    __syncthreads();
  }
}

// ---------------- launcher ----------------
extern "C" void kernel_launch(void* const* d_in, const int* in_sizes, int n_in,
                              void* d_out, int out_size, void* d_ws, size_t ws_size,
                              hipStream_t stream) {
  const float* x    = (const float*)d_in[0];
  const float* Wq   = (const float*)d_in[1];
  const float* bq   = (const float*)d_in[2];
  const float* Wk   = (const float*)d_in[3];
  const float* bk   = (const float*)d_in[4];
  const float* Wv   = (const float*)d_in[5];
  const float* bv   = (const float*)d_in[6];
  const float* Wo   = (const float*)d_in[7];
  const float* bo   = (const float*)d_in[8];
  const float* ln_g = (const float*)d_in[9];
  const float* ln_b = (const float*)d_in[10];

  char* ws = (char*)d_ws;
  size_t SZ = (size_t)MROWS * DDIM * 2;
  unsigned short* hbuf = (unsigned short*)ws;
  unsigned short* qbuf = (unsigned short*)(ws + SZ);
  char* p = ws + 2 * SZ;
  unsigned short* wf   = (unsigned short*)p;  p += (size_t)1536 * 512 * 2;
  unsigned short* wob  = (unsigned short*)p;  p += (size_t)512 * 512 * 2;
  float* biasf         = (float*)p;           p += 1536 * 4;
  p = (char*)(((uintptr_t)p + 255) & ~(uintptr_t)255);
  unsigned short* part = (unsigned short*)p;  p += (size_t)32 * KVCH * PTILE * 2;   // 25.5 MB
  unsigned short* kvD  = (unsigned short*)p;  p += (size_t)32 * 4096 * 2;
  float* ksum          = (float*)p;           p += 32 * 64 * 4;
  p = (char*)(((uintptr_t)p + 255) & ~(uintptr_t)255);
  unsigned short* Bmat = (unsigned short*)p;  p += (size_t)BATCH * 512 * 512 * 2;

  wprep<<<(786432 + 262144 + 1536 + 255) / 256, 256, 0, stream>>>(Wq, bq, Wk, bk, Wv, bv, Wo,
                                                                  wf, wob, biasf);
  ln_kernel<<<MROWS / 4, 256, 0, stream>>>(x, ln_g, ln_b, hbuf);
  qkv_gemm<<<MPNL * 12, 512, 0, stream>>>(hbuf, wf, biasf, qbuf, part);
  kv_final<<<dim3(32, 3), 256, 0, stream>>>(part, kvD, ksum);
  w2_gemm<<<32, 512, 0, stream>>>(kvD, wob, Bmat);
  qscale<<<MROWS / 4, 256, 0, stream>>>(qbuf, ksum);
  ogemm<<<MPNL * 4, 512, 0, stream>>>(qbuf, Bmat, bo, x, (float*)d_out);
}